// Round 3
// baseline (289.312 us; speedup 1.0000x reference)
//
#include <hip/hip_runtime.h>
#include <hip/hip_fp16.h>

// FrameConsistencyLoss: mean over (N,64) of (proj_a - proj_b)^2,
// proj_x[i] = x[i] @ W[ids_x[i]] + b[ids_x[i]]; N=2e6, REL_DIM=14, CAN_DIM=64, 4 experts.
//
// R7: global_load_lds DMA staging -- no destination VGPRs, no spills.
//  R6 post-mortem: coalescing was confounded by 97.7MB of scratch spill
//  traffic (RawRegs didn't fit the 64-VGPR budget the compiler picked).
//  R4==R5 proved occupancy is not the lever; per-CU throughput is pinned at
//  ~2100 cy/chunk with every counter <10% => VMEM frontend serialization.
//  This round removes both failure modes at once:
//   * 7x __builtin_amdgcn_global_load_lds width=16 per chunk DMA the dense
//     3584B A/B regions straight into LDS (lane-linear; one mixed call covers
//     A-tail + B-head via per-lane global addresses). Zero dest VGPRs.
//   * staging (7168B) and packed-f16 (9216B) are disjoint: DMA(n) overlaps
//     compute(c); s_waitcnt vmcnt(0) before pack_scatter(n). 16384B/block
//     => 10 blocks/CU (R4/R5 showed >=8 is sufficient).
//  Per-wave DS ops are in-order (invariant harness-verified in R5/R6), so
//  pack's P-writes can't bypass compute's P-reads: zero barriers.
//
//   Row r: diff_emb[k]: window 14*ea..+13 gets +a (f16), window 14*eb..+13 gets -b,
//   one-hot +1 at k=56+ea, -1 at k=56+eb (bias rows of W~); if ea==eb the windows
//   merge to (a-b) and the one-hots cancel. D = diff_emb @ W~ via 2 chained
//   mfma_f32_16x16x32_f16 per (row-tile, col-tile); loss += sum(D^2).

#define N_ROWS   2000000
#define N_CHUNKS (N_ROWS / 64)   // 31250 chunks of 64 rows
#define NBLK     2560            // 10 blocks/CU x 256 CUs, persistent
#define LDSW     36              // dwords per packed LDS row (64 ushorts + 8 pad)
#define P_OFF    1792            // dword offset of packed region (byte 7168)

typedef _Float16     h8 __attribute__((ext_vector_type(8)));
typedef float        f4 __attribute__((ext_vector_type(4)));
typedef unsigned int u4 __attribute__((ext_vector_type(4)));

typedef __attribute__((address_space(3))) unsigned int       lds_u32;
typedef __attribute__((address_space(1))) const unsigned int glb_u32;

__device__ __forceinline__ unsigned int pkrtz(float a, float b) {
    return __builtin_bit_cast(unsigned int, __builtin_amdgcn_cvt_pkrtz(a, b));
}

// DMA 64 lanes x 16B: LDS dest = uniform base + lane*16; global src per-lane.
__device__ __forceinline__ void dma16(const void* g, unsigned int* l) {
    __builtin_amdgcn_global_load_lds((const glb_u32*)g, (lds_u32*)l, 16, 0, 0);
}

// Stage chunk c's raw f32 rows into S: A bytes [0,3584), B bytes [3584,7168).
// 7 width-16 DMAs; call 4 mixes A-tail (lanes 0..31) and B-head (lanes 32..63).
__device__ __forceinline__ void dma_chunk(unsigned int* S, int lane,
                                          const char* pa, const char* pb) {
#pragma unroll
    for (int j = 0; j < 3; ++j)
        dma16(pa + j * 1024 + lane * 16, S + j * 256);          // A [0,3072)
    const char* gm = (lane < 32) ? (pa + 3072 + lane * 16)
                                 : (pb + (lane - 32) * 16);
    dma16(gm, S + 768);                                          // A-tail + B-head
#pragma unroll
    for (int j = 0; j < 3; ++j)
        dma16(pb + 512 + j * 1024 + lane * 16, S + 1024 + j * 256); // B [512,3584)
}

// Row re-gather from staged f32 (stride-56B b64 reads, 2-way-max bank alias =
// free) + pack to f16 + scatter into packed row at dword P_OFF + lane*LDSW.
__device__ __forceinline__ void pack_scatter(unsigned int* __restrict__ S, int lane,
                                             int ea, int eb) {
    const float* sa = (const float*)S + 14 * lane;          // 8B-aligned
    const float* sb = (const float*)S + 896 + 14 * lane;
    unsigned int pa[7], pb[7];
    const bool same = (ea == eb);
#pragma unroll
    for (int t = 0; t < 7; ++t) {
        float2 av = *(const float2*)(sa + 2 * t);
        float2 bv = *(const float2*)(sb + 2 * t);
        float sx = same ? (av.x - bv.x) : av.x;
        float sy = same ? (av.y - bv.y) : av.y;
        pa[t] = pkrtz(sx, sy);
        pb[t] = pkrtz(-bv.x, -bv.y);
    }
    unsigned int* row32 = S + P_OFF + lane * LDSW;
    const u4 z = {0u, 0u, 0u, 0u};
#pragma unroll
    for (int t = 0; t < 8; ++t) ((u4*)row32)[t] = z;        // zero k=0..63
#pragma unroll
    for (int t = 0; t < 7; ++t) row32[7 * ea + t] = pa[t];  // +a (or a-b if same)
    if (!same) {
#pragma unroll
        for (int t = 0; t < 7; ++t) row32[7 * eb + t] = pb[t];
        const unsigned wa = 0x3C00u << ((ea & 1) * 16);     // +1.0h at k=56+ea
        const unsigned wb = 0xBC00u << ((eb & 1) * 16);     // -1.0h at k=56+eb
        const int ja = 28 + (ea >> 1), jb = 28 + (eb >> 1);
        if (ja == jb) row32[ja] = wa | wb;
        else { row32[ja] = wa; row32[jb] = wb; }
    }
}

__device__ __forceinline__ void compute_chunk(const unsigned int* __restrict__ S,
                                              int sub, int quad, const h8* wf,
                                              float* ls) {
#pragma unroll
    for (int t = 0; t < 4; ++t) {
        const unsigned int* fr = S + P_OFF + (t * 16 + sub) * LDSW + quad * 4;
        u4 lo = *(const u4*)fr;          // k = quad*8 .. +7
        u4 hi = *(const u4*)(fr + 16);   // k = 32+quad*8 .. +7
        const h8 e0 = __builtin_bit_cast(h8, lo);
        const h8 e1 = __builtin_bit_cast(h8, hi);
#pragma unroll
        for (int ct = 0; ct < 4; ++ct) {
            const f4 z = {0.0f, 0.0f, 0.0f, 0.0f};
            f4 acc = __builtin_amdgcn_mfma_f32_16x16x32_f16(e0, wf[ct * 2 + 0], z, 0, 0, 0);
            acc     = __builtin_amdgcn_mfma_f32_16x16x32_f16(e1, wf[ct * 2 + 1], acc, 0, 0, 0);
#pragma unroll
            for (int rr = 0; rr < 4; ++rr)
                ls[rr] = fmaf(acc[rr], acc[rr], ls[rr]);
        }
    }
}

__global__ void __launch_bounds__(64, 2)
frame_loss(const float* __restrict__ A, const float* __restrict__ B,
           const int* __restrict__ IDA, const int* __restrict__ IDB,
           const float* __restrict__ W, const float* __restrict__ BIAS,
           float* __restrict__ ws)
{
    // 16384B: staged f32 [dw 0,1792) ; packed f16 rows [dw 1792, 4096).
    __shared__ alignas(16) unsigned int S[4096];

    const int lane = threadIdx.x;        // block = 1 wave
    const int sub  = lane & 15;
    const int quad = lane >> 4;

    // ---- W~ B-fragments in registers (once): frag f=ct*2+s, elem j:
    // k = s*32 + quad*8 + j, col c = ct*16 + sub. W~[k][c] = W (k<56), bias (56..59), 0.
    h8 wf[8];
#pragma unroll
    for (int ct = 0; ct < 4; ++ct)
#pragma unroll
        for (int s = 0; s < 2; ++s) {
            h8 f;
            const int c = ct * 16 + sub;
#pragma unroll
            for (int j = 0; j < 8; ++j) {
                const int k = s * 32 + quad * 8 + j;
                float v = 0.0f;
                if (k < 56)       v = W[k * 64 + c];           // (4,14,64) flat == W~ rows 0..55
                else if (k < 60)  v = BIAS[(k - 56) * 64 + c]; // bias rows 56..59
                f[j] = (_Float16)v;
            }
            wf[ct * 2 + s] = f;
        }

    float ls[4] = {0.0f, 0.0f, 0.0f, 0.0f};
    const int stride = gridDim.x;
    const char* Ac = (const char*)A;
    const char* Bc = (const char*)B;

    int c = blockIdx.x;
    dma_chunk(S, lane, Ac + (size_t)c * 3584, Bc + (size_t)c * 3584);
    int ea = IDA[c * 64 + lane];
    int eb = IDB[c * 64 + lane];
    asm volatile("s_waitcnt vmcnt(0)" ::: "memory");   // DMA(c) + ids landed
    pack_scatter(S, lane, ea, eb);

    int n = c + stride;
    bool more = (n < N_CHUNKS);
    if (more) {   // S is dead after pack_scatter consumed it -> refill early
        dma_chunk(S, lane, Ac + (size_t)n * 3584, Bc + (size_t)n * 3584);
        ea = IDA[n * 64 + lane];
        eb = IDB[n * 64 + lane];
    }

    while (true) {
        compute_chunk(S, sub, quad, wf, ls);           // reads P only; DMA in flight
        if (!more) break;
        asm volatile("s_waitcnt vmcnt(0)" ::: "memory");  // DMA(n) landed in S
        pack_scatter(S, lane, ea, eb);                 // S(n) -> P(n); DS in-order vs compute reads
        c = n; n = c + stride; more = (n < N_CHUNKS);
        if (more) {
            dma_chunk(S, lane, Ac + (size_t)n * 3584, Bc + (size_t)n * 3584);
            ea = IDA[n * 64 + lane];
            eb = IDB[n * 64 + lane];
        }
    }

    float lsum = ls[0] + ls[1] + ls[2] + ls[3];
#pragma unroll
    for (int off = 32; off > 0; off >>= 1)
        lsum += __shfl_down(lsum, off, 64);
    if (lane == 0)
        ws[blockIdx.x] = lsum;     // no atomic: per-block partial
}

__global__ void __launch_bounds__(256)
reduce_partials(const float* __restrict__ ws, float* __restrict__ out, int nblk)
{
    const int tid = threadIdx.x;
    float s = 0.0f;
    for (int i = tid; i < nblk; i += 256) s += ws[i];
#pragma unroll
    for (int off = 32; off > 0; off >>= 1)
        s += __shfl_down(s, off, 64);
    __shared__ float tmp[4];
    if ((tid & 63) == 0) tmp[tid >> 6] = s;
    __syncthreads();
    if (tid == 0)
        out[0] = (tmp[0] + tmp[1] + tmp[2] + tmp[3]) * (1.0f / 128000000.0f); // 1/(N*64)
}

extern "C" void kernel_launch(void* const* d_in, const int* in_sizes, int n_in,
                              void* d_out, int out_size, void* d_ws, size_t ws_size,
                              hipStream_t stream) {
    const float* A    = (const float*)d_in[0];
    const float* B    = (const float*)d_in[1];
    const int*   IDA  = (const int*)d_in[2];
    const int*   IDB  = (const int*)d_in[3];
    const float* W    = (const float*)d_in[4];
    const float* BIAS = (const float*)d_in[5];
    float* ws  = (float*)d_ws;     // needs NBLK*4 = 10 KB of scratch
    float* out = (float*)d_out;

    // fall back to a 2048-block grid if the workspace is unexpectedly small
    const int nblk = (ws_size >= (size_t)NBLK * sizeof(float)) ? NBLK : 2048;

    frame_loss<<<dim3(nblk), dim3(64), 0, stream>>>(A, B, IDA, IDB, W, BIAS, ws);
    reduce_partials<<<dim3(1), dim3(256), 0, stream>>>(ws, out, nblk);
}